// Round 11
// baseline (2368.670 us; speedup 1.0000x reference)
//
#include <hip/hip_runtime.h>
#include <stdint.h>

#define NE 195480
#define NM 10242
#define NG 65160
#define DD 512
#define NOUT 471

typedef __attribute__((ext_vector_type(8))) short bf16x8;
typedef __attribute__((ext_vector_type(4))) float f32x4;
typedef __attribute__((ext_vector_type(8))) unsigned short ushort8;

__device__ __forceinline__ float bf2f(unsigned short u) {
    union { unsigned int i; float f; } v; v.i = ((unsigned int)u) << 16; return v.f;
}
__device__ __forceinline__ unsigned short f2bf(float f) {
    union { float f; unsigned int u; } v; v.f = f;
    unsigned int x = v.u;
    return (unsigned short)((x + 0x7fffu + ((x >> 16) & 1u)) >> 16);
}
__device__ __forceinline__ float silu_f(float x) { return x / (1.f + __expf(-x)); }

__device__ __forceinline__ ushort8 cvt8(const float* __restrict__ p) {
    const f32x4 lo = *(const f32x4*)p;
    const f32x4 hi = *(const f32x4*)(p + 4);
    ushort8 r;
    #pragma unroll
    for (int j = 0; j < 4; ++j) { r[j] = f2bf(lo[j]); r[j + 4] = f2bf(hi[j]); }
    return r;
}

// async global->LDS, 16B per lane. LDS dest lane-linear; global src per-lane.
__device__ __forceinline__ void gl_lds16(const unsigned short* g, unsigned short* l) {
    __builtin_amdgcn_global_load_lds(
        (const __attribute__((address_space(1))) unsigned int*)g,
        (__attribute__((address_space(3))) unsigned int*)l, 16, 0, 0);
}

enum { A_PLAIN = 0, A_EDGE = 1, A_NODE = 2 };
enum { E_BIAS_BF16 = 0, E_SILU_BF16 = 1, E_EADD_BF16 = 2, E_RESID_BF16 = 3, E_OUT_F32 = 4 };

// C = epilogue(A @ B + bias), 128x128 tile, BK=64, 4 waves (2x2).
// 1D grid + bijective chunked XCD swizzle: orig = (wgid%8)*(nwg/8)+wgid/8.
// R10 diagnosis: with (bn fast, bm) 2D grid, the 4 bn-blocks sharing an
// A-panel round-robin onto 4 DIFFERENT XCDs (private L2s) -> A fetched 4x
// from HBM (G3 FETCH 1.1 GB vs ~0.3 ideal). Chunked swizzle gives each XCD a
// contiguous orig-id range -> same-bm blocks co-run on one XCD, panel hits L2.
// nbn is fixed at 4 (all N <= 512): bn = orig & 3, bm = orig >> 2.
template<int AMODE, int EPI>
__global__ __launch_bounds__(256)
void gemm128(const unsigned short* __restrict__ Asrc,   // PLAIN: A | EDGE: meshB | NODE: gridB
             const unsigned short* __restrict__ Asrc2,  // EDGE: gridB | NODE: aggB
             const unsigned short* __restrict__ Asrc3,  // EDGE: e0
             const unsigned short* __restrict__ Bw,     // bf16 [512][K]
             const float* __restrict__ bias,
             int M, int N, int K,
             const float* __restrict__ gridres,         // E_RESID residual (f32)
             const unsigned short* __restrict__ e0res,  // E_EADD residual (bf16)
             const int* __restrict__ esrc,
             const int* __restrict__ edst,
             unsigned short* __restrict__ outB,
             float* __restrict__ outF)
{
    __shared__ unsigned short As[128 * 64];
    __shared__ unsigned short Bs[128 * 64];

    const int tid  = threadIdx.x;
    const int nwg  = gridDim.x;
    int orig = blockIdx.x;
    if ((nwg & 7) == 0) {                       // bijective chunked XCD swizzle
        const int q = nwg >> 3;
        orig = (blockIdx.x & 7) * q + (blockIdx.x >> 3);
    }
    const int bn = orig & 3;
    const int bm = orig >> 2;

    const int w    = tid >> 6;
    const int lane = tid & 63;
    const int quad = lane >> 4;
    const int ln   = lane & 15;
    const int wr   = w >> 1;
    const int wc   = w & 1;

    const int srow = tid >> 3;    // 0..31
    const int sc   = tid & 7;     // 0..7
    const int ck   = (sc ^ (srow & 7)) * 8;   // swizzled source chunk (elems)

    int arowc[4], gsrc[4], gdst[4];
    #pragma unroll
    for (int i = 0; i < 4; ++i) {
        int r = bm * 128 + i * 32 + srow;
        arowc[i] = (r < M) ? r : (M - 1);
        if (AMODE == A_EDGE) { gsrc[i] = esrc[arowc[i]]; gdst[i] = edst[arowc[i]]; }
    }

    f32x4 acc[4][4] = {};

    for (int k0 = 0; k0 < K; k0 += 64) {
        __syncthreads();   // previous compute done reading LDS
        #pragma unroll
        for (int i = 0; i < 4; ++i) {
            const int row = i * 32 + srow;
            const unsigned short* ga;
            if (AMODE == A_PLAIN) {
                ga = Asrc + (size_t)arowc[i] * K + k0 + ck;
            } else if (AMODE == A_EDGE) {
                if (k0 < 512)       ga = Asrc  + (size_t)gsrc[i] * 512 + k0 + ck;
                else if (k0 < 1024) ga = Asrc2 + (size_t)gdst[i] * 512 + (k0 - 512) + ck;
                else                ga = Asrc3 + (size_t)arowc[i] * 512 + (k0 - 1024) + ck;
            } else { // A_NODE
                if (k0 < 512)       ga = Asrc  + (size_t)arowc[i] * 512 + k0 + ck;
                else                ga = Asrc2 + (size_t)arowc[i] * 512 + (k0 - 512) + ck;
            }
            gl_lds16(ga, As + i * 2048 + tid * 8);
            gl_lds16(Bw + (size_t)(bn * 128 + row) * K + k0 + ck, Bs + i * 2048 + tid * 8);
        }
        __syncthreads();   // vmcnt(0) drained before barrier -> staged

        #pragma unroll
        for (int kt = 0; kt < 2; ++kt) {
            bf16x8 af[4], bfv[4];
            #pragma unroll
            for (int m = 0; m < 4; ++m) {
                const int r = wr * 64 + m * 16 + ln;
                af[m] = *(const bf16x8*)(As + r * 64 + (((kt * 4 + quad) ^ (r & 7)) * 8));
            }
            #pragma unroll
            for (int n = 0; n < 4; ++n) {
                const int r = wc * 64 + n * 16 + ln;
                bfv[n] = *(const bf16x8*)(Bs + r * 64 + (((kt * 4 + quad) ^ (r & 7)) * 8));
            }
            #pragma unroll
            for (int m = 0; m < 4; ++m)
                #pragma unroll
                for (int n = 0; n < 4; ++n)
                    acc[m][n] = __builtin_amdgcn_mfma_f32_16x16x32_bf16(af[m], bfv[n], acc[m][n], 0, 0, 0);
        }
    }

    // ---- epilogue ----
    #pragma unroll
    for (int n = 0; n < 4; ++n) {
        const int col_g = bn * 128 + wc * 64 + n * 16 + ln;
        const bool col_ok = (col_g < N);
        const float bcol = col_ok ? bias[col_g] : 0.f;
        #pragma unroll
        for (int m = 0; m < 4; ++m) {
            #pragma unroll
            for (int r = 0; r < 4; ++r) {
                const int row_g = bm * 128 + wr * 64 + m * 16 + quad * 4 + r;
                if (row_g >= M || !col_ok) continue;
                float v = acc[m][n][r] + bcol;
                if (EPI == E_BIAS_BF16) {
                    outB[(size_t)row_g * N + col_g] = f2bf(v);
                } else if (EPI == E_SILU_BF16) {
                    outB[(size_t)row_g * N + col_g] = f2bf(silu_f(v));
                } else if (EPI == E_EADD_BF16) {
                    v += bf2f(e0res[(size_t)row_g * 512 + col_g]);  // e = e0 + mlp
                    outB[(size_t)row_g * 512 + col_g] = f2bf(v);    // in-place over e0
                } else if (EPI == E_RESID_BF16) {
                    v += gridres[(size_t)row_g * 512 + col_g];
                    outB[(size_t)row_g * N + col_g] = f2bf(v);
                } else { // E_OUT_F32
                    outF[(size_t)row_g * N + col_g] = v;
                }
            }
        }
    }
}

// Transpose-convert weights: w f32 [K][N] -> wT bf16 [Npad][K], zero-padded.
__global__ __launch_bounds__(256)
void wconv(const float* __restrict__ w, unsigned short* __restrict__ wT,
           int K, int N, int Npad)
{
    __shared__ float t[64][65];
    const int tid = threadIdx.x;
    const int bk = blockIdx.x * 64, bn = blockIdx.y * 64;
    const int cc = tid & 63, rr = tid >> 6;
    #pragma unroll
    for (int i = 0; i < 16; ++i) {
        const int k = rr + i * 4;
        float v = 0.f;
        if (bk + k < K && bn + cc < N) v = w[(size_t)(bk + k) * N + bn + cc];
        t[k][cc] = v;
    }
    __syncthreads();
    #pragma unroll
    for (int i = 0; i < 16; ++i) {
        const int n = rr + i * 4;
        if (bn + n < Npad && bk + cc < K)
            wT[(size_t)(bn + n) * K + bk + cc] = f2bf(t[cc][n]);
    }
}

// flat f32 -> bf16 convert, 8 elems/thread
__global__ __launch_bounds__(256)
void cvtb(const float* __restrict__ in, unsigned short* __restrict__ out, long long n8)
{
    const long long i = (long long)blockIdx.x * 256 + threadIdx.x;
    if (i >= n8) return;
    *(ushort8*)(out + i * 8) = cvt8(in + i * 8);
}

// h = silu(attrs @ emb_w0 + emb_b0), K=4
__global__ __launch_bounds__(256)
void embed_l1(const float* __restrict__ attrs,
              const float* __restrict__ w0,
              const float* __restrict__ b0,
              unsigned short* __restrict__ h)
{
    const long long idx = (long long)blockIdx.x * 256 + threadIdx.x;
    if (idx >= (long long)NE * 512) return;
    const int row = (int)(idx >> 9);
    const int c = (int)(idx & 511);
    float acc = b0[c];
    #pragma unroll
    for (int k = 0; k < 4; ++k)
        acc += attrs[row * 4 + k] * w0[k * 512 + c];
    h[idx] = f2bf(silu_f(acc));
}

// Per-dst-node slot lists: fill[d] counter + slots[d][0..63] edge ids.
__global__ __launch_bounds__(256)
void fillslots(const int* __restrict__ edst, unsigned* __restrict__ fill,
               unsigned* __restrict__ slots)
{
    const int i = blockIdx.x * 256 + threadIdx.x;
    if (i >= NE) return;
    const int d = edst[i];
    const unsigned p = atomicAdd(&fill[d], 1u);
    if (p < 64u) slots[(size_t)d * 64 + p] = (unsigned)i;
}

// aggB[g] = sum over edges with dst g of e[eid] (bf16 rows, f32 accum).
__global__ __launch_bounds__(256)
void segsum(const unsigned short* __restrict__ e,
            const unsigned* __restrict__ fill,
            const unsigned* __restrict__ slots,
            unsigned short* __restrict__ aggB)
{
    const int g = blockIdx.x;
    const int c = threadIdx.x;
    unsigned deg = fill[g]; if (deg > 64u) deg = 64u;
    float a0 = 0.f, a1 = 0.f;
    for (unsigned j = 0; j < deg; ++j) {
        const unsigned short* row = e + (size_t)slots[(size_t)g * 64 + j] * 512;
        a0 += bf2f(row[c]);
        a1 += bf2f(row[c + 256]);
    }
    aggB[(size_t)g * 512 + c]       = f2bf(a0);
    aggB[(size_t)g * 512 + c + 256] = f2bf(a1);
}

extern "C" void kernel_launch(void* const* d_in, const int* in_sizes, int n_in,
                              void* d_out, int out_size, void* d_ws, size_t ws_size,
                              hipStream_t stream)
{
    const float* mesh    = (const float*)d_in[0];
    const float* gridf   = (const float*)d_in[1];
    const float* attrs   = (const float*)d_in[2];
    const int*   esrc    = (const int*)d_in[3];
    const int*   edst    = (const int*)d_in[4];
    const float* emb_w0  = (const float*)d_in[5];
    const float* emb_b0  = (const float*)d_in[6];
    const float* emb_w1  = (const float*)d_in[7];
    const float* emb_b1  = (const float*)d_in[8];
    const float* edge_w0 = (const float*)d_in[9];
    const float* edge_b0 = (const float*)d_in[10];
    const float* edge_w1 = (const float*)d_in[11];
    const float* edge_b1 = (const float*)d_in[12];
    const float* node_w0 = (const float*)d_in[13];
    const float* node_b0 = (const float*)d_in[14];
    const float* node_w1 = (const float*)d_in[15];
    const float* node_b1 = (const float*)d_in[16];
    const float* out_w0  = (const float*)d_in[17];
    const float* out_b0  = (const float*)d_in[18];
    const float* out_w1  = (const float*)d_in[19];
    const float* out_b1  = (const float*)d_in[20];

    // ws (534 MB baseline footprint): e0/e/g2 (200 MB) | hb (200 MB) | r3 (133 MB)
    //   r3: aggB bf16 (66.7) | out_w1T (0.5) | fill (0.26) | slots (16.7)
    // d_out (122.8 MB) scratch until G8: 6 wT weights + meshB + gridB (81.9 MB).
    char* ws = (char*)d_ws;
    unsigned short* e0  = (unsigned short*)ws;            // e0 -> e (in-place) -> g2
    unsigned short* hb  = (unsigned short*)(ws + (size_t)NE * 512 * 2);
    char*           r3  = ws + (size_t)2 * NE * 512 * 2;  // 133,447,680 B region
    unsigned short* g2  = e0;

    unsigned short* aggB    = (unsigned short*)r3;              // 66,723,840 B
    unsigned short* out_w1T = (unsigned short*)(r3 + 66723840); //    524,288 B
    unsigned*       fillA   = (unsigned*)(r3 + 67248128);       //    260,640 B
    unsigned*       slots   = (unsigned*)(r3 + 67508768);       // 16,680,960 B

    unsigned short* wTp = (unsigned short*)d_out;
    unsigned short* emb_w1T  = wTp;                       // 512*512
    unsigned short* edge_w0T = emb_w1T  + 512 * 512;      // 512*1536
    unsigned short* edge_w1T = edge_w0T + 512 * 1536;     // 512*512
    unsigned short* node_w0T = edge_w1T + 512 * 512;      // 512*1024
    unsigned short* node_w1T = node_w0T + 512 * 1024;     // 512*512
    unsigned short* out_w0T  = node_w1T + 512 * 512;      // 512*512
    unsigned short* meshB    = out_w0T  + 512 * 512;      // NM*512
    unsigned short* gridB    = meshB + (size_t)NM * 512;  // NG*512

    hipMemsetAsync(fillA, 0, (size_t)NG * sizeof(unsigned), stream);

    dim3 blk(256);
    { dim3 g( 8, 8); wconv<<<g, blk, 0, stream>>>(emb_w1,  emb_w1T,   512, 512, 512); }
    { dim3 g(24, 8); wconv<<<g, blk, 0, stream>>>(edge_w0, edge_w0T, 1536, 512, 512); }
    { dim3 g( 8, 8); wconv<<<g, blk, 0, stream>>>(edge_w1, edge_w1T,  512, 512, 512); }
    { dim3 g(16, 8); wconv<<<g, blk, 0, stream>>>(node_w0, node_w0T, 1024, 512, 512); }
    { dim3 g( 8, 8); wconv<<<g, blk, 0, stream>>>(node_w1, node_w1T,  512, 512, 512); }
    { dim3 g( 8, 8); wconv<<<g, blk, 0, stream>>>(out_w0,  out_w0T,   512, 512, 512); }
    { dim3 g( 8, 8); wconv<<<g, blk, 0, stream>>>(out_w1,  out_w1T,   512, 471, 512); }
    cvtb<<<(int)(((long long)NM * 512 / 8 + 255) / 256), blk, 0, stream>>>(mesh,  meshB, (long long)NM * 512 / 8);
    cvtb<<<(int)(((long long)NG * 512 / 8 + 255) / 256), blk, 0, stream>>>(gridf, gridB, (long long)NG * 512 / 8);
    fillslots<<<(NE + 255) / 256, blk, 0, stream>>>(edst, fillA, slots);

    // L1: hb = silu(attrs @ emb_w0 + b)
    embed_l1<<<(int)(((long long)NE * 512 + 255) / 256), blk, 0, stream>>>(attrs, emb_w0, emb_b0, hb);

    const int gmE = (NE + 127) / 128;   // 1528
    const int gmG = (NG + 127) / 128;   // 510
    const int nwgE = 4 * gmE;           // 6112 (div by 8)
    const int nwgG = 4 * gmG;           // 2040 (div by 8)

    // G2: e0 = hb @ emb_w1 + b
    gemm128<A_PLAIN, E_BIAS_BF16><<<nwgE, blk, 0, stream>>>(hb, nullptr, nullptr, emb_w1T, emb_b1,
        NE, 512, 512, nullptr, nullptr, nullptr, nullptr, e0, nullptr);
    // G3: hb = silu([meshB[src] | gridB[dst] | e0] @ edge_w0 + b)
    gemm128<A_EDGE, E_SILU_BF16><<<nwgE, blk, 0, stream>>>(meshB, gridB, e0, edge_w0T, edge_b0,
        NE, 512, 1536, nullptr, nullptr, esrc, edst, hb, nullptr);
    // G4: e = e0 + hb @ edge_w1 + b   (bf16, in-place over e0)
    gemm128<A_PLAIN, E_EADD_BF16><<<nwgE, blk, 0, stream>>>(hb, nullptr, nullptr, edge_w1T, edge_b1,
        NE, 512, 512, nullptr, e0, nullptr, nullptr, e0, nullptr);
    // segment-sum by gather: aggB[g] = sum e[slots[g]]
    segsum<<<NG, blk, 0, stream>>>(e0, fillA, slots, aggB);
    // G5: hb = silu([gridB | aggB] @ node_w0 + b)
    gemm128<A_NODE, E_SILU_BF16><<<nwgG, blk, 0, stream>>>(gridB, aggB, nullptr, node_w0T, node_b0,
        NG, 512, 1024, nullptr, nullptr, nullptr, nullptr, hb, nullptr);
    // G6: g2 = grid + hb @ node_w1 + b
    gemm128<A_PLAIN, E_RESID_BF16><<<nwgG, blk, 0, stream>>>(hb, nullptr, nullptr, node_w1T, node_b1,
        NG, 512, 512, gridf, nullptr, nullptr, nullptr, g2, nullptr);
    // G7: hb = silu(g2 @ out_w0 + b)
    gemm128<A_PLAIN, E_SILU_BF16><<<nwgG, blk, 0, stream>>>(g2, nullptr, nullptr, out_w0T, out_b0,
        NG, 512, 512, nullptr, nullptr, nullptr, nullptr, hb, nullptr);
    // G8: out = hb @ out_w1 + b (fp32, N=471; overwrites all d_out scratch)
    gemm128<A_PLAIN, E_OUT_F32><<<nwgG, blk, 0, stream>>>(hb, nullptr, nullptr, out_w1T, out_b1,
        NG, NOUT, 512, nullptr, nullptr, nullptr, nullptr, nullptr, (float*)d_out);
}

// Round 12
// 1860.460 us; speedup vs baseline: 1.2732x; 1.2732x over previous
//
#include <hip/hip_runtime.h>
#include <stdint.h>

#define NE 195480
#define NM 10242
#define NG 65160
#define DD 512
#define NOUT 471

typedef __attribute__((ext_vector_type(8))) short bf16x8;
typedef __attribute__((ext_vector_type(4))) float f32x4;
typedef __attribute__((ext_vector_type(8))) unsigned short ushort8;

__device__ __forceinline__ float bf2f(unsigned short u) {
    union { unsigned int i; float f; } v; v.i = ((unsigned int)u) << 16; return v.f;
}
__device__ __forceinline__ unsigned short f2bf(float f) {
    union { float f; unsigned int u; } v; v.f = f;
    unsigned int x = v.u;
    return (unsigned short)((x + 0x7fffu + ((x >> 16) & 1u)) >> 16);
}
__device__ __forceinline__ float silu_f(float x) { return x / (1.f + __expf(-x)); }

__device__ __forceinline__ ushort8 cvt8(const float* __restrict__ p) {
    const f32x4 lo = *(const f32x4*)p;
    const f32x4 hi = *(const f32x4*)(p + 4);
    ushort8 r;
    #pragma unroll
    for (int j = 0; j < 4; ++j) { r[j] = f2bf(lo[j]); r[j + 4] = f2bf(hi[j]); }
    return r;
}

// async global->LDS, 16B per lane. LDS dest lane-linear; global src per-lane.
__device__ __forceinline__ void gl_lds16(const unsigned short* g, unsigned short* l) {
    __builtin_amdgcn_global_load_lds(
        (const __attribute__((address_space(1))) unsigned int*)g,
        (__attribute__((address_space(3))) unsigned int*)l, 16, 0, 0);
}

enum { A_PLAIN = 0, A_EDGE = 1, A_NODE = 2 };
enum { E_BIAS_BF16 = 0, E_SILU_BF16 = 1, E_AGG_BF16 = 2, E_RESID_BF16 = 3, E_OUT_F32 = 4 };

// C = epilogue(A @ B + bias), 128x128 tile, BK=64, 4 waves (2x2).
// 1D grid + bijective chunked XCD swizzle (R11: FETCH 1.1GB->345MB verified).
// m97-style global_load_lds staging, source-chunk swizzle, 0 bank conflicts.
// E_AGG_BF16: v = acc + deg[row]*bias[col] (agg = [s1|s3]@[emb_w1;edge_w1]
//             + deg*(emb_b1+edge_b1), the linear refactor of the edge chain).
// ldOut: store row stride for bf16 epilogues (BwG3 seg2 needs 1536).
template<int AMODE, int EPI>
__global__ __launch_bounds__(256)
void gemm128(const unsigned short* __restrict__ Asrc,   // PLAIN: A | EDGE: meshB | NODE: src0
             const unsigned short* __restrict__ Asrc2,  // EDGE: gridB | NODE: src1
             const unsigned short* __restrict__ Asrc3,  // EDGE: h1
             const unsigned short* __restrict__ Bw,     // bf16 [512][K]
             const float* __restrict__ bias,
             int M, int N, int K, int ldOut,
             const float* __restrict__ gridres,         // E_RESID residual (f32, stride 512)
             const int* __restrict__ esrc,
             const int* __restrict__ edst,
             const unsigned* __restrict__ degA,         // E_AGG: per-row edge count
             unsigned short* __restrict__ outB,
             float* __restrict__ outF)
{
    __shared__ unsigned short As[128 * 64];
    __shared__ unsigned short Bs[128 * 64];

    const int tid  = threadIdx.x;
    const int nwg  = gridDim.x;
    int orig = blockIdx.x;
    if ((nwg & 7) == 0) {                       // bijective chunked XCD swizzle
        const int q = nwg >> 3;
        orig = (blockIdx.x & 7) * q + (blockIdx.x >> 3);
    }
    const int bn = orig & 3;
    const int bm = orig >> 2;

    const int w    = tid >> 6;
    const int lane = tid & 63;
    const int quad = lane >> 4;
    const int ln   = lane & 15;
    const int wr   = w >> 1;
    const int wc   = w & 1;

    const int srow = tid >> 3;    // 0..31
    const int sc   = tid & 7;     // 0..7
    const int ck   = (sc ^ (srow & 7)) * 8;   // swizzled source chunk (elems)

    int arowc[4], gsrc[4], gdst[4];
    #pragma unroll
    for (int i = 0; i < 4; ++i) {
        int r = bm * 128 + i * 32 + srow;
        arowc[i] = (r < M) ? r : (M - 1);
        if (AMODE == A_EDGE) { gsrc[i] = esrc[arowc[i]]; gdst[i] = edst[arowc[i]]; }
    }

    f32x4 acc[4][4] = {};

    for (int k0 = 0; k0 < K; k0 += 64) {
        __syncthreads();   // previous compute done reading LDS
        #pragma unroll
        for (int i = 0; i < 4; ++i) {
            const int row = i * 32 + srow;
            const unsigned short* ga;
            if (AMODE == A_PLAIN) {
                ga = Asrc + (size_t)arowc[i] * K + k0 + ck;
            } else if (AMODE == A_EDGE) {
                if (k0 < 512)       ga = Asrc  + (size_t)gsrc[i] * 512 + k0 + ck;
                else if (k0 < 1024) ga = Asrc2 + (size_t)gdst[i] * 512 + (k0 - 512) + ck;
                else                ga = Asrc3 + (size_t)arowc[i] * 512 + (k0 - 1024) + ck;
            } else { // A_NODE: [src0 | src1] both bf16
                if (k0 < 512)       ga = Asrc  + (size_t)arowc[i] * 512 + k0 + ck;
                else                ga = Asrc2 + (size_t)arowc[i] * 512 + (k0 - 512) + ck;
            }
            gl_lds16(ga, As + i * 2048 + tid * 8);
            gl_lds16(Bw + (size_t)(bn * 128 + row) * K + k0 + ck, Bs + i * 2048 + tid * 8);
        }
        __syncthreads();   // vmcnt(0) drained before barrier -> staged

        #pragma unroll
        for (int kt = 0; kt < 2; ++kt) {
            bf16x8 af[4], bfv[4];
            #pragma unroll
            for (int m = 0; m < 4; ++m) {
                const int r = wr * 64 + m * 16 + ln;
                af[m] = *(const bf16x8*)(As + r * 64 + (((kt * 4 + quad) ^ (r & 7)) * 8));
            }
            #pragma unroll
            for (int n = 0; n < 4; ++n) {
                const int r = wc * 64 + n * 16 + ln;
                bfv[n] = *(const bf16x8*)(Bs + r * 64 + (((kt * 4 + quad) ^ (r & 7)) * 8));
            }
            #pragma unroll
            for (int m = 0; m < 4; ++m)
                #pragma unroll
                for (int n = 0; n < 4; ++n)
                    acc[m][n] = __builtin_amdgcn_mfma_f32_16x16x32_bf16(af[m], bfv[n], acc[m][n], 0, 0, 0);
        }
    }

    // ---- epilogue ----
    #pragma unroll
    for (int n = 0; n < 4; ++n) {
        const int col_g = bn * 128 + wc * 64 + n * 16 + ln;
        const bool col_ok = (col_g < N);
        const float bcol = col_ok ? bias[col_g] : 0.f;
        #pragma unroll
        for (int m = 0; m < 4; ++m) {
            #pragma unroll
            for (int r = 0; r < 4; ++r) {
                const int row_g = bm * 128 + wr * 64 + m * 16 + quad * 4 + r;
                if (row_g >= M || !col_ok) continue;
                float v = acc[m][n][r];
                if (EPI == E_AGG_BF16) v += (float)degA[row_g] * bcol;
                else                   v += bcol;
                if (EPI == E_BIAS_BF16 || EPI == E_AGG_BF16) {
                    outB[(size_t)row_g * ldOut + col_g] = f2bf(v);
                } else if (EPI == E_SILU_BF16) {
                    outB[(size_t)row_g * ldOut + col_g] = f2bf(silu_f(v));
                } else if (EPI == E_RESID_BF16) {
                    v += gridres[(size_t)row_g * 512 + col_g];
                    outB[(size_t)row_g * ldOut + col_g] = f2bf(v);
                } else { // E_OUT_F32
                    outF[(size_t)row_g * N + col_g] = v;
                }
            }
        }
    }
}

// Transpose-convert: w f32 [K][N] -> wT bf16 [Npad][K-slice], row stride ldT.
__global__ __launch_bounds__(256)
void wconv(const float* __restrict__ w, unsigned short* __restrict__ wT,
           int K, int N, int Npad, int ldT)
{
    __shared__ float t[64][65];
    const int tid = threadIdx.x;
    const int bk = blockIdx.x * 64, bn = blockIdx.y * 64;
    const int cc = tid & 63, rr = tid >> 6;
    #pragma unroll
    for (int i = 0; i < 16; ++i) {
        const int k = rr + i * 4;
        float v = 0.f;
        if (bk + k < K && bn + cc < N) v = w[(size_t)(bk + k) * N + bn + cc];
        t[k][cc] = v;
    }
    __syncthreads();
    #pragma unroll
    for (int i = 0; i < 16; ++i) {
        const int n = rr + i * 4;
        if (bn + n < Npad && bk + cc < K)
            wT[(size_t)(bn + n) * ldT + bk + cc] = f2bf(t[cc][n]);
    }
}

// flat f32 -> bf16 convert, 8 elems/thread
__global__ __launch_bounds__(256)
void cvtb(const float* __restrict__ in, unsigned short* __restrict__ out, long long n8)
{
    const long long i = (long long)blockIdx.x * 256 + threadIdx.x;
    if (i >= n8) return;
    *(ushort8*)(out + i * 8) = cvt8(in + i * 8);
}

// h1 = silu(attrs @ emb_w0 + emb_b0), K=4
__global__ __launch_bounds__(256)
void embed_l1(const float* __restrict__ attrs,
              const float* __restrict__ w0,
              const float* __restrict__ b0,
              unsigned short* __restrict__ h)
{
    const long long idx = (long long)blockIdx.x * 256 + threadIdx.x;
    if (idx >= (long long)NE * 512) return;
    const int row = (int)(idx >> 9);
    const int c = (int)(idx & 511);
    float acc = b0[c];
    #pragma unroll
    for (int k = 0; k < 4; ++k)
        acc += attrs[row * 4 + k] * w0[k * 512 + c];
    h[idx] = f2bf(silu_f(acc));
}

// Per-dst-node slot lists: fill[d] counter + slots[d][0..63] edge ids.
__global__ __launch_bounds__(256)
void fillslots(const int* __restrict__ edst, unsigned* __restrict__ fill,
               unsigned* __restrict__ slots)
{
    const int i = blockIdx.x * 256 + threadIdx.x;
    if (i >= NE) return;
    const int d = edst[i];
    const unsigned p = atomicAdd(&fill[d], 1u);
    if (p < 64u) slots[(size_t)d * 64 + p] = (unsigned)i;
}

// Fused segment-sums of BOTH h1 and hb3 (bf16 rows, f32 accum).
__global__ __launch_bounds__(256)
void segsum2(const unsigned short* __restrict__ h1,
             const unsigned short* __restrict__ h3,
             const unsigned* __restrict__ fill,
             const unsigned* __restrict__ slots,
             unsigned short* __restrict__ s1,
             unsigned short* __restrict__ s3)
{
    const int g = blockIdx.x;
    const int c = threadIdx.x;
    unsigned deg = fill[g]; if (deg > 64u) deg = 64u;
    float a0 = 0.f, a1 = 0.f, b0 = 0.f, b1 = 0.f;
    for (unsigned j = 0; j < deg; ++j) {
        const size_t row = (size_t)slots[(size_t)g * 64 + j] * 512;
        a0 += bf2f(h1[row + c]);
        a1 += bf2f(h1[row + c + 256]);
        b0 += bf2f(h3[row + c]);
        b1 += bf2f(h3[row + c + 256]);
    }
    s1[(size_t)g * 512 + c]       = f2bf(a0);
    s1[(size_t)g * 512 + c + 256] = f2bf(a1);
    s3[(size_t)g * 512 + c]       = f2bf(b0);
    s3[(size_t)g * 512 + c + 256] = f2bf(b1);
}

// b''[j] = edge_b0[j] + sum_c emb_b1[c]*W3[c][j];  bsum[j] = emb_b1[j]+edge_b1[j]
__global__ __launch_bounds__(256)
void biasfold(const float* __restrict__ edge_b0, const float* __restrict__ emb_b1,
              const float* __restrict__ w3, const float* __restrict__ edge_b1,
              float* __restrict__ bpp, float* __restrict__ bsum)
{
    const int j = blockIdx.x * 256 + threadIdx.x;
    if (j >= 512) return;
    float a = edge_b0[j];
    for (int c = 0; c < 512; ++c) a += emb_b1[c] * w3[(size_t)c * 512 + j];
    bpp[j]  = a;
    bsum[j] = emb_b1[j] + edge_b1[j];
}

extern "C" void kernel_launch(void* const* d_in, const int* in_sizes, int n_in,
                              void* d_out, int out_size, void* d_ws, size_t ws_size,
                              hipStream_t stream)
{
    const float* mesh    = (const float*)d_in[0];
    const float* gridf   = (const float*)d_in[1];
    const float* attrs   = (const float*)d_in[2];
    const int*   esrc    = (const int*)d_in[3];
    const int*   edst    = (const int*)d_in[4];
    const float* emb_w0  = (const float*)d_in[5];
    const float* emb_b0  = (const float*)d_in[6];
    const float* emb_w1  = (const float*)d_in[7];
    const float* emb_b1  = (const float*)d_in[8];
    const float* edge_w0 = (const float*)d_in[9];
    const float* edge_b0 = (const float*)d_in[10];
    const float* edge_w1 = (const float*)d_in[11];
    const float* edge_b1 = (const float*)d_in[12];
    const float* node_w0 = (const float*)d_in[13];
    const float* node_b0 = (const float*)d_in[14];
    const float* node_w1 = (const float*)d_in[15];
    const float* node_b1 = (const float*)d_in[16];
    const float* out_w0  = (const float*)d_in[17];
    const float* out_b0  = (const float*)d_in[18];
    const float* out_w1  = (const float*)d_in[19];
    const float* out_b1  = (const float*)d_in[20];

    // ws (534 MB baseline footprint):
    //  region1 (200 MB): h1 -> (dead after segsum2) aggB (67 MB) -> (dead
    //           after G5) g2 (67 MB)
    //  region2 (200 MB): hb3 -> (dead after segsum2) hb (G5/G7 outputs)
    //  r3 (133 MB): s1 (66.7) | s3 (66.7)  [exact]; after GA both dead ->
    //           out_w1T at r3 base (read by G8).
    // d_out (122.8 MB) scratch until G8 (~100 MB used), fully overwritten by G8.
    char* ws = (char*)d_ws;
    unsigned short* h1  = (unsigned short*)ws;
    unsigned short* hb  = (unsigned short*)(ws + (size_t)NE * 512 * 2);
    char*           r3  = ws + (size_t)2 * NE * 512 * 2;   // 133,447,680 B
    unsigned short* aggB = h1;                             // after h1 dead
    unsigned short* g2   = h1;                             // after aggB dead
    unsigned short* s1   = (unsigned short*)r3;
    unsigned short* s3   = (unsigned short*)(r3 + 66723840);
    unsigned short* out_w1T = (unsigned short*)r3;         // after s1/s3 dead

    char* sc = (char*)d_out;                               // scratch until G8
    unsigned short* BwG3     = (unsigned short*)sc;                 // [512][1536]
    unsigned short* BwGA     = (unsigned short*)(sc +  1572864);    // [512][1024]
    unsigned short* node_w0T = (unsigned short*)(sc +  2621440);    // [512][1024]
    unsigned short* node_w1T = (unsigned short*)(sc +  3670016);    // [512][512]
    unsigned short* out_w0T  = (unsigned short*)(sc +  4194304);    // [512][512]
    unsigned short* W3T      = (unsigned short*)(sc +  4718592);    // [512][512]
    unsigned short* emb_w1b  = (unsigned short*)(sc +  5242880);    // [512][512]
    unsigned short* meshB    = (unsigned short*)(sc +  5767168);    // NM*512
    unsigned short* gridB    = (unsigned short*)(sc + 16254976);    // NG*512
    unsigned*       fillA    = (unsigned*)      (sc + 82978816);    // NG u32
    float*          zbias    = (float*)         (sc + 83239456);    // 512 f32
    float*          bpp      = (float*)         (sc + 83241504);    // 512 f32
    float*          bsum     = (float*)         (sc + 83243552);    // 512 f32
    unsigned*       slots    = (unsigned*)      (sc + 83245600);    // NG*64 u32 (ends ~99.9MB)

    // zero fillA + zbias (contiguous)
    hipMemsetAsync(fillA, 0, 260640 + 2048, stream);

    dim3 blk(256);
    // weight prep (all into d_out scratch)
    { dim3 g(16, 8); wconv<<<g, blk, 0, stream>>>(edge_w0, BwG3, 1024, 512, 512, 1536); }           // seg0/1
    { dim3 g( 8, 8); wconv<<<g, blk, 0, stream>>>(edge_w0 + (size_t)1024 * 512, W3T, 512, 512, 512, 512); }
    { dim3 g( 8, 8); wconv<<<g, blk, 0, stream>>>(emb_w1,  BwGA,       512, 512, 512, 1024); }      // GA k<512
    { dim3 g( 8, 8); wconv<<<g, blk, 0, stream>>>(edge_w1, BwGA + 512, 512, 512, 512, 1024); }      // GA k>=512
    { dim3 g(16, 8); wconv<<<g, blk, 0, stream>>>(node_w0, node_w0T, 1024, 512, 512, 1024); }
    { dim3 g( 8, 8); wconv<<<g, blk, 0, stream>>>(node_w1, node_w1T,  512, 512, 512, 512); }
    { dim3 g( 8, 8); wconv<<<g, blk, 0, stream>>>(out_w0,  out_w0T,   512, 512, 512, 512); }
    cvtb<<<128, blk, 0, stream>>>(emb_w1, emb_w1b, 512 * 512 / 8);
    cvtb<<<(int)(((long long)NM * 512 / 8 + 255) / 256), blk, 0, stream>>>(mesh,  meshB, (long long)NM * 512 / 8);
    cvtb<<<(int)(((long long)NG * 512 / 8 + 255) / 256), blk, 0, stream>>>(gridf, gridB, (long long)NG * 512 / 8);
    fillslots<<<(NE + 255) / 256, blk, 0, stream>>>(edst, fillA, slots);
    biasfold<<<2, blk, 0, stream>>>(edge_b0, emb_b1, edge_w0 + (size_t)1024 * 512, edge_b1, bpp, bsum);

    // W' = emb_w1 @ W3 folded into BwG3 seg2: C[j][d] -> BwG3[j*1536+1024+d]
    gemm128<A_PLAIN, E_BIAS_BF16><<<16, blk, 0, stream>>>(W3T, nullptr, nullptr, emb_w1b, zbias,
        512, 512, 512, 1536, nullptr, nullptr, nullptr, nullptr, BwG3 + 1024, nullptr);

    // L1: h1 = silu(attrs @ emb_w0 + b)
    embed_l1<<<(int)(((long long)NE * 512 + 255) / 256), blk, 0, stream>>>(attrs, emb_w0, emb_b0, h1);

    const int gmE = (NE + 127) / 128;   // 1528
    const int gmG = (NG + 127) / 128;   // 510
    const int nwgE = 4 * gmE;           // 6112 (div 8)
    const int nwgG = 4 * gmG;           // 2040 (div 8)

    // G3': hb3 = silu(mesh[src]@W1 + grid[dst]@W2 + h1@W' + b'')   (K=1536)
    gemm128<A_EDGE, E_SILU_BF16><<<nwgE, blk, 0, stream>>>(meshB, gridB, h1, BwG3, bpp,
        NE, 512, 1536, 512, nullptr, esrc, edst, nullptr, hb, nullptr);
    // fused segment-sums: s1 = seg(h1), s3 = seg(hb3)
    segsum2<<<NG, blk, 0, stream>>>(h1, hb, fillA, slots, s1, s3);
    // GA: aggB = [s1|s3] @ [emb_w1; edge_w1] + deg*(emb_b1+edge_b1)   (K=1024)
    gemm128<A_NODE, E_AGG_BF16><<<nwgG, blk, 0, stream>>>(s1, s3, nullptr, BwGA, bsum,
        NG, 512, 1024, 512, nullptr, nullptr, nullptr, fillA, aggB, nullptr);
    // s1/s3 dead -> out_w1T into r3 for G8
    { dim3 g( 8, 8); wconv<<<g, blk, 0, stream>>>(out_w1, out_w1T, 512, 471, 512, 512); }
    // G5: hb = silu([gridB | aggB] @ node_w0 + b)
    gemm128<A_NODE, E_SILU_BF16><<<nwgG, blk, 0, stream>>>(gridB, aggB, nullptr, node_w0T, node_b0,
        NG, 512, 1024, 512, nullptr, nullptr, nullptr, nullptr, hb, nullptr);
    // G6: g2 = grid + hb @ node_w1 + b
    gemm128<A_PLAIN, E_RESID_BF16><<<nwgG, blk, 0, stream>>>(hb, nullptr, nullptr, node_w1T, node_b1,
        NG, 512, 512, 512, gridf, nullptr, nullptr, nullptr, g2, nullptr);
    // G7: hb = silu(g2 @ out_w0 + b)
    gemm128<A_PLAIN, E_SILU_BF16><<<nwgG, blk, 0, stream>>>(g2, nullptr, nullptr, out_w0T, out_b0,
        NG, 512, 512, 512, nullptr, nullptr, nullptr, nullptr, hb, nullptr);
    // G8: out = hb @ out_w1 + b (fp32, N=471; overwrites all d_out scratch)
    gemm128<A_PLAIN, E_OUT_F32><<<nwgG, blk, 0, stream>>>(hb, nullptr, nullptr, out_w1T, out_b1,
        NG, NOUT, 512, NOUT, nullptr, nullptr, nullptr, nullptr, nullptr, (float*)d_out);
}